// Round 6
// baseline (168.341 us; speedup 1.0000x reference)
//
#include <hip/hip_runtime.h>
#include <hip/hip_bf16.h>

#define D 128           // D_IN == D_OUT == 128
#define GEMM_ROWS 32    // fallback tier only

typedef __bf16 bf16x8 __attribute__((ext_vector_type(8)));
typedef float  f32x4  __attribute__((ext_vector_type(4)));
typedef unsigned int u32x4 __attribute__((ext_vector_type(4)));

// ---------------------------------------------------------------------------
// K1 (UNCHANGED control): fused GEMM + row_ptr.
// ---------------------------------------------------------------------------
__device__ inline bf16x8 cvt_a8(const float* __restrict__ p) {
    float4 v0 = ((const float4*)p)[0], v1 = ((const float4*)p)[1];
    bf16x8 a;
    a[0] = (__bf16)v0.x; a[1] = (__bf16)v0.y; a[2] = (__bf16)v0.z; a[3] = (__bf16)v0.w;
    a[4] = (__bf16)v1.x; a[5] = (__bf16)v1.y; a[6] = (__bf16)v1.z; a[7] = (__bf16)v1.w;
    return a;
}

__global__ __launch_bounds__(256) void fused_gemm_rp(
        const float* __restrict__ x, const float* __restrict__ w,
        const int* __restrict__ rows,
        unsigned short* __restrict__ h, int* __restrict__ rp,
        int n_nodes, int n_edges, int gemm_blocks) {
    const int b = blockIdx.x;

    if (b >= gemm_blocks) {           // ---- row_ptr builder blocks ----
        int e = (b - gemm_blocks) * 256 + threadIdx.x;
        if (e >= n_edges) return;
        int r    = rows[e];
        int prev = (e == 0) ? -1 : rows[e - 1];
        for (int rr = prev + 1; rr <= r; ++rr) rp[rr] = e;
        if (e == n_edges - 1)
            for (int rr = r + 1; rr <= n_nodes; ++rr) rp[rr] = n_edges;
        return;
    }

    const int wave = threadIdx.x >> 6;
    const int lane = threadIdx.x & 63;
    const int m16  = lane & 15;
    const int q    = lane >> 4;

    const int row0 = b * 64;
    const int col0 = wave * 32;

    bf16x8 bfr[2][4];
#pragma unroll
    for (int t = 0; t < 2; ++t)
#pragma unroll
        for (int s = 0; s < 4; ++s) {
            const float* wp = w + (size_t)(32 * s + q * 8) * D + col0 + 16 * t + m16;
#pragma unroll
            for (int j = 0; j < 8; ++j)
                bfr[t][s][j] = (__bf16)wp[(size_t)j * D];
        }

#pragma unroll 1
    for (int sl = 0; sl < 4; ++sl) {
        const int r = row0 + sl * 16 + m16;
        const float* xp = x + (size_t)r * D + q * 8;

        bf16x8 a[4];
        if (r < n_nodes) {
#pragma unroll
            for (int s = 0; s < 4; ++s) a[s] = cvt_a8(xp + 32 * s);
        } else {
#pragma unroll
            for (int s = 0; s < 4; ++s)
#pragma unroll
                for (int j = 0; j < 8; ++j) a[s][j] = (__bf16)0.f;
        }

        f32x4 acc0 = (f32x4)0.f, acc1 = (f32x4)0.f;
#pragma unroll
        for (int s = 0; s < 4; ++s) {
            acc0 = __builtin_amdgcn_mfma_f32_16x16x32_bf16(a[s], bfr[0][s], acc0, 0, 0, 0);
            acc1 = __builtin_amdgcn_mfma_f32_16x16x32_bf16(a[s], bfr[1][s], acc1, 0, 0, 0);
        }

#pragma unroll
        for (int i = 0; i < 4; ++i) {
            int row = row0 + sl * 16 + q * 4 + i;
            h[(size_t)row * D + col0 + m16]      = __builtin_bit_cast(unsigned short, (__bf16)acc0[i]);
            h[(size_t)row * D + col0 + 16 + m16] = __builtin_bit_cast(unsigned short, (__bf16)acc1[i]);
        }
    }
}

// ---------------------------------------------------------------------------
// K2: XCD-sliced SpMM. D split into 4 col-slices of 32 (64B bf16). With
// round-robin block->XCD dispatch, slice = blockIdx&3 pins each XCD to one
// 3.2 MB h-slice -> fits its private 4 MB L2 (h whole = 12.8 MB doesn't).
// Wave = one row-slice: 16 edge-chains x 4 lanes x 16B (16 outstanding
// gathers; deg~16 row finishes in ~1 round-trip). cols/vals read 4x (cached).
// ---------------------------------------------------------------------------
__global__ __launch_bounds__(256) void spmm_sliced(
        const unsigned short* __restrict__ h,
        const int* __restrict__ row_ptr,
        const int* __restrict__ cols,
        const float* __restrict__ vals,
        float* __restrict__ out, int n) {
    const int slice = blockIdx.x & 3;       // cycles fastest -> one slice/XCD
    const int rg    = blockIdx.x >> 2;
    const int wave  = threadIdx.x >> 6;
    const int lane  = threadIdx.x & 63;
    const int r     = rg * 4 + wave;
    if (r >= n) return;

    const int start = row_ptr[r];
    const int end   = row_ptr[r + 1];
    const int chain = lane >> 2;            // 16 chains
    const int l4    = lane & 3;             // 16B slot within 64B slice

    const u32x4* h4 = (const u32x4*)h;      // 16 u32x4 per row
    const int base = slice * 4 + l4;        // this lane's u32x4 within the row

    float acc[8];
#pragma unroll
    for (int j = 0; j < 8; ++j) acc[j] = 0.f;

    int e = start + chain;
    int c = 0; float v = 0.f;
    if (e < end) { c = cols[e]; v = vals[e]; }
    while (e < end) {
        int en = e + 16; int cn = 0; float vn = 0.f;
        if (en < end) { cn = cols[en]; vn = vals[en]; }     // overlaps gather
        u32x4 hv = h4[(size_t)c * (D / 8) + base];
#pragma unroll
        for (int j = 0; j < 4; ++j) {
            unsigned int u = hv[j];
            float lo = __builtin_bit_cast(float, u << 16);
            float hi = __builtin_bit_cast(float, u & 0xFFFF0000u);
            acc[2 * j]     = fmaf(v, lo, acc[2 * j]);
            acc[2 * j + 1] = fmaf(v, hi, acc[2 * j + 1]);
        }
        c = cn; v = vn; e = en;
    }

    // combine 16 chains (chain index lives in lane bits 2..5)
#pragma unroll
    for (int j = 0; j < 8; ++j) {
        acc[j] += __shfl_xor(acc[j], 4);
        acc[j] += __shfl_xor(acc[j], 8);
        acc[j] += __shfl_xor(acc[j], 16);
        acc[j] += __shfl_xor(acc[j], 32);
    }

    if (chain == 0) {                       // lanes 0..3 -> 128B contiguous
        float4 o0, o1;
        o0.x = fmaxf(acc[0], 0.f); o0.y = fmaxf(acc[1], 0.f);
        o0.z = fmaxf(acc[2], 0.f); o0.w = fmaxf(acc[3], 0.f);
        o1.x = fmaxf(acc[4], 0.f); o1.y = fmaxf(acc[5], 0.f);
        o1.z = fmaxf(acc[6], 0.f); o1.w = fmaxf(acc[7], 0.f);
        float4* op = (float4*)(out + (size_t)r * D + slice * 32 + l4 * 8);
        op[0] = o0; op[1] = o1;
    }
}

// ============================ fallback tiers ===============================
__global__ __launch_bounds__(256) void gemm128(const float* __restrict__ x,
                                               const float* __restrict__ w,
                                               float* __restrict__ h, int n) {
    __shared__ float4 ws4[D * D / 4];
    __shared__ float  xs[GEMM_ROWS][D];
    const int tid  = threadIdx.x;
    const int row0 = blockIdx.x * GEMM_ROWS;
    const float4* w4 = (const float4*)w;
    for (int i = tid; i < D * D / 4; i += 256) ws4[i] = w4[i];
    float4* xs4 = (float4*)&xs[0][0];
    const float4* x4 = (const float4*)x;
    for (int i = tid; i < GEMM_ROWS * D / 4; i += 256) {
        int row = row0 + (i >> 5);
        float4 v = make_float4(0.f, 0.f, 0.f, 0.f);
        if (row < n) v = x4[(size_t)row0 * (D / 4) + i];
        xs4[i] = v;
    }
    __syncthreads();
    const int tx = tid & 31, ty = tid >> 5;
    float4 acc[4];
#pragma unroll
    for (int i = 0; i < 4; ++i) acc[i] = make_float4(0.f, 0.f, 0.f, 0.f);
#pragma unroll 8
    for (int k = 0; k < D; ++k) {
        float4 wv = ws4[k * (D / 4) + tx];
#pragma unroll
        for (int i = 0; i < 4; ++i) {
            float xv = xs[ty * 4 + i][k];
            acc[i].x = fmaf(xv, wv.x, acc[i].x);
            acc[i].y = fmaf(xv, wv.y, acc[i].y);
            acc[i].z = fmaf(xv, wv.z, acc[i].z);
            acc[i].w = fmaf(xv, wv.w, acc[i].w);
        }
    }
#pragma unroll
    for (int i = 0; i < 4; ++i) {
        int row = row0 + ty * 4 + i;
        if (row < n) ((float4*)(h + (size_t)row * D))[tx] = acc[i];
    }
}

__global__ __launch_bounds__(128) void spmm_row(const float* __restrict__ h,
                                                const int* __restrict__ rows,
                                                const int* __restrict__ cols,
                                                const float* __restrict__ vals,
                                                float* __restrict__ out, int n_edges) {
    const int r = blockIdx.x, d = threadIdx.x;
    int lo = 0, hi = n_edges;
    while (lo < hi) { int m = (lo + hi) >> 1; if (rows[m] < r) lo = m + 1; else hi = m; }
    const int start = lo;
    hi = n_edges;
    while (lo < hi) { int m = (lo + hi) >> 1; if (rows[m] <= r) lo = m + 1; else hi = m; }
    const int end = lo;
    float acc = 0.f;
    for (int e = start; e < end; ++e)
        acc = fmaf(vals[e], h[(size_t)cols[e] * D + d], acc);
    out[(size_t)r * D + d] = fmaxf(acc, 0.f);
}

__global__ __launch_bounds__(128) void fused_fallback(
        const float* __restrict__ x, const float* __restrict__ w,
        const int* __restrict__ rows, const int* __restrict__ cols,
        const float* __restrict__ vals, float* __restrict__ out, int n_edges) {
    const int r = blockIdx.x, d = threadIdx.x;
    int lo = 0, hi = n_edges;
    while (lo < hi) { int m = (lo + hi) >> 1; if (rows[m] < r) lo = m + 1; else hi = m; }
    const int start = lo;
    hi = n_edges;
    while (lo < hi) { int m = (lo + hi) >> 1; if (rows[m] <= r) lo = m + 1; else hi = m; }
    const int end = lo;
    float acc = 0.f;
    for (int e = start; e < end; ++e) {
        int c = cols[e]; float v = vals[e];
        float hcd = 0.f;
        for (int k = 0; k < D; ++k)
            hcd = fmaf(x[(size_t)c * D + k], w[(size_t)k * D + d], hcd);
        acc = fmaf(v, hcd, acc);
    }
    out[(size_t)r * D + d] = fmaxf(acc, 0.f);
}

// ===========================================================================
extern "C" void kernel_launch(void* const* d_in, const int* in_sizes, int n_in,
                              void* d_out, int out_size, void* d_ws, size_t ws_size,
                              hipStream_t stream) {
    const float* x    = (const float*)d_in[0];
    const float* w    = (const float*)d_in[1];
    const int*   rows = (const int*)d_in[2];
    const int*   cols = (const int*)d_in[3];
    const float* vals = (const float*)d_in[4];
    float* out = (float*)d_out;

    const int n_nodes = in_sizes[0] / D;              // 50000
    const int n_edges = in_sizes[2];                  // 800000
    const int n_pad   = (n_nodes + 63) & ~63;         // 50048

    const size_t h_bytes  = (size_t)n_pad * D * sizeof(unsigned short);  // 12.8 MB
    const size_t rp_off   = h_bytes;
    const size_t need     = rp_off + (size_t)(n_nodes + 1) * sizeof(int);
    const size_t hf_bytes = (size_t)n_nodes * D * sizeof(float);

    if (ws_size >= need) {
        unsigned short* h  = (unsigned short*)d_ws;
        int*            rp = (int*)((char*)d_ws + rp_off);

        const int gemm_blocks = n_pad / 64;                      // 782
        const int rp_blocks   = (n_edges + 255) / 256;           // 3125
        fused_gemm_rp<<<gemm_blocks + rp_blocks, 256, 0, stream>>>(
            x, w, rows, h, rp, n_nodes, n_edges, gemm_blocks);

        const int rgroups = (n_nodes + 3) / 4;                   // 12500
        spmm_sliced<<<rgroups * 4, 256, 0, stream>>>(h, rp, cols, vals, out, n_nodes);
    } else if (ws_size >= hf_bytes) {
        float* hf = (float*)d_ws;
        gemm128<<<(n_nodes + GEMM_ROWS - 1) / GEMM_ROWS, 256, 0, stream>>>(x, w, hf, n_nodes);
        spmm_row<<<n_nodes, 128, 0, stream>>>(hf, rows, cols, vals, out, n_edges);
    } else {
        fused_fallback<<<n_nodes, 128, 0, stream>>>(x, w, rows, cols, vals, out, n_edges);
    }
}

// Round 7
// 128.429 us; speedup vs baseline: 1.3108x; 1.3108x over previous
//
#include <hip/hip_runtime.h>
#include <hip/hip_bf16.h>

#define D 128           // D_IN == D_OUT == 128
#define GEMM_ROWS 32    // fallback tier only

typedef __bf16 bf16x8 __attribute__((ext_vector_type(8)));
typedef float  f32x4  __attribute__((ext_vector_type(4)));
typedef unsigned int u32x4 __attribute__((ext_vector_type(4)));

// ---------------------------------------------------------------------------
// K1 (UNCHANGED control): fused GEMM + row_ptr.
// ---------------------------------------------------------------------------
__device__ inline bf16x8 cvt_a8(const float* __restrict__ p) {
    float4 v0 = ((const float4*)p)[0], v1 = ((const float4*)p)[1];
    bf16x8 a;
    a[0] = (__bf16)v0.x; a[1] = (__bf16)v0.y; a[2] = (__bf16)v0.z; a[3] = (__bf16)v0.w;
    a[4] = (__bf16)v1.x; a[5] = (__bf16)v1.y; a[6] = (__bf16)v1.z; a[7] = (__bf16)v1.w;
    return a;
}

__global__ __launch_bounds__(256) void fused_gemm_rp(
        const float* __restrict__ x, const float* __restrict__ w,
        const int* __restrict__ rows,
        unsigned short* __restrict__ h, int* __restrict__ rp,
        int n_nodes, int n_edges, int gemm_blocks) {
    const int b = blockIdx.x;

    if (b >= gemm_blocks) {           // ---- row_ptr builder blocks ----
        int e = (b - gemm_blocks) * 256 + threadIdx.x;
        if (e >= n_edges) return;
        int r    = rows[e];
        int prev = (e == 0) ? -1 : rows[e - 1];
        for (int rr = prev + 1; rr <= r; ++rr) rp[rr] = e;
        if (e == n_edges - 1)
            for (int rr = r + 1; rr <= n_nodes; ++rr) rp[rr] = n_edges;
        return;
    }

    const int wave = threadIdx.x >> 6;
    const int lane = threadIdx.x & 63;
    const int m16  = lane & 15;
    const int q    = lane >> 4;

    const int row0 = b * 64;
    const int col0 = wave * 32;

    bf16x8 bfr[2][4];
#pragma unroll
    for (int t = 0; t < 2; ++t)
#pragma unroll
        for (int s = 0; s < 4; ++s) {
            const float* wp = w + (size_t)(32 * s + q * 8) * D + col0 + 16 * t + m16;
#pragma unroll
            for (int j = 0; j < 8; ++j)
                bfr[t][s][j] = (__bf16)wp[(size_t)j * D];
        }

#pragma unroll 1
    for (int sl = 0; sl < 4; ++sl) {
        const int r = row0 + sl * 16 + m16;
        const float* xp = x + (size_t)r * D + q * 8;

        bf16x8 a[4];
        if (r < n_nodes) {
#pragma unroll
            for (int s = 0; s < 4; ++s) a[s] = cvt_a8(xp + 32 * s);
        } else {
#pragma unroll
            for (int s = 0; s < 4; ++s)
#pragma unroll
                for (int j = 0; j < 8; ++j) a[s][j] = (__bf16)0.f;
        }

        f32x4 acc0 = (f32x4)0.f, acc1 = (f32x4)0.f;
#pragma unroll
        for (int s = 0; s < 4; ++s) {
            acc0 = __builtin_amdgcn_mfma_f32_16x16x32_bf16(a[s], bfr[0][s], acc0, 0, 0, 0);
            acc1 = __builtin_amdgcn_mfma_f32_16x16x32_bf16(a[s], bfr[1][s], acc1, 0, 0, 0);
        }

#pragma unroll
        for (int i = 0; i < 4; ++i) {
            int row = row0 + sl * 16 + q * 4 + i;
            h[(size_t)row * D + col0 + m16]      = __builtin_bit_cast(unsigned short, (__bf16)acc0[i]);
            h[(size_t)row * D + col0 + 16 + m16] = __builtin_bit_cast(unsigned short, (__bf16)acc1[i]);
        }
    }
}

// ---------------------------------------------------------------------------
// K2: SpMM on bf16 h — R5 structure (4 chains x 16 lanes x 16B, NO slicing)
// + BATCH-2 gathers: each chain issues TWO h-gathers back-to-back before any
// FMA consumes them -> 2x in-flight gather bytes per wave (R5 sat exactly at
// the latency-concurrency product: ~1 gather/wave in flight). Dummy gathers
// (c=0, v=0) on the tail contribute 0 -> correctness unaffected, ~6% extra
// traffic at Poisson(16) degrees.
// ---------------------------------------------------------------------------
__global__ __launch_bounds__(256) void spmm_bf16_b2(
        const unsigned short* __restrict__ h,
        const int* __restrict__ row_ptr,
        const int* __restrict__ cols,
        const float* __restrict__ vals,
        float* __restrict__ out, int n) {
    const int wave = threadIdx.x >> 6;
    const int lane = threadIdx.x & 63;
    const int r = blockIdx.x * 4 + wave;
    if (r >= n) return;

    const int start = row_ptr[r];
    const int end   = row_ptr[r + 1];
    const int chain = lane >> 4;    // 4 edge chains, stride 4
    const int l4    = lane & 15;    // 16B slot: dims [l4*8, l4*8+8)

    const u32x4* h4 = (const u32x4*)h;
    float acc[8];
#pragma unroll
    for (int j = 0; j < 8; ++j) acc[j] = 0.f;

    int e = start + chain;
    int c0 = 0, c1 = 0; float v0 = 0.f, v1 = 0.f;
    if (e < end)     { c0 = cols[e];     v0 = vals[e]; }
    if (e + 4 < end) { c1 = cols[e + 4]; v1 = vals[e + 4]; }

    while (e < end) {
        // prefetch next batch's indices (overlaps the two gathers below)
        int en = e + 8;
        int cn0 = 0, cn1 = 0; float vn0 = 0.f, vn1 = 0.f;
        if (en < end)     { cn0 = cols[en];     vn0 = vals[en]; }
        if (en + 4 < end) { cn1 = cols[en + 4]; vn1 = vals[en + 4]; }

        // both gathers in flight before either is consumed
        u32x4 hv0 = h4[(size_t)c0 * (D / 8) + l4];
        u32x4 hv1 = h4[(size_t)c1 * (D / 8) + l4];

#pragma unroll
        for (int j = 0; j < 4; ++j) {
            unsigned int u = hv0[j];
            acc[2 * j]     = fmaf(v0, __builtin_bit_cast(float, u << 16),         acc[2 * j]);
            acc[2 * j + 1] = fmaf(v0, __builtin_bit_cast(float, u & 0xFFFF0000u), acc[2 * j + 1]);
        }
#pragma unroll
        for (int j = 0; j < 4; ++j) {
            unsigned int u = hv1[j];
            acc[2 * j]     = fmaf(v1, __builtin_bit_cast(float, u << 16),         acc[2 * j]);
            acc[2 * j + 1] = fmaf(v1, __builtin_bit_cast(float, u & 0xFFFF0000u), acc[2 * j + 1]);
        }
        c0 = cn0; v0 = vn0; c1 = cn1; v1 = vn1; e = en;
    }

    // combine 4 chains (chain index in lane bits 4,5)
#pragma unroll
    for (int j = 0; j < 8; ++j) {
        acc[j] += __shfl_xor(acc[j], 16);
        acc[j] += __shfl_xor(acc[j], 32);
    }

    if (chain == 0) {
        float4 o0, o1;
        o0.x = fmaxf(acc[0], 0.f); o0.y = fmaxf(acc[1], 0.f);
        o0.z = fmaxf(acc[2], 0.f); o0.w = fmaxf(acc[3], 0.f);
        o1.x = fmaxf(acc[4], 0.f); o1.y = fmaxf(acc[5], 0.f);
        o1.z = fmaxf(acc[6], 0.f); o1.w = fmaxf(acc[7], 0.f);
        float4* op = (float4*)(out + (size_t)r * D + l4 * 8);
        op[0] = o0; op[1] = o1;
    }
}

// ============================ fallback tiers ===============================
__global__ __launch_bounds__(256) void gemm128(const float* __restrict__ x,
                                               const float* __restrict__ w,
                                               float* __restrict__ h, int n) {
    __shared__ float4 ws4[D * D / 4];
    __shared__ float  xs[GEMM_ROWS][D];
    const int tid  = threadIdx.x;
    const int row0 = blockIdx.x * GEMM_ROWS;
    const float4* w4 = (const float4*)w;
    for (int i = tid; i < D * D / 4; i += 256) ws4[i] = w4[i];
    float4* xs4 = (float4*)&xs[0][0];
    const float4* x4 = (const float4*)x;
    for (int i = tid; i < GEMM_ROWS * D / 4; i += 256) {
        int row = row0 + (i >> 5);
        float4 v = make_float4(0.f, 0.f, 0.f, 0.f);
        if (row < n) v = x4[(size_t)row0 * (D / 4) + i];
        xs4[i] = v;
    }
    __syncthreads();
    const int tx = tid & 31, ty = tid >> 5;
    float4 acc[4];
#pragma unroll
    for (int i = 0; i < 4; ++i) acc[i] = make_float4(0.f, 0.f, 0.f, 0.f);
#pragma unroll 8
    for (int k = 0; k < D; ++k) {
        float4 wv = ws4[k * (D / 4) + tx];
#pragma unroll
        for (int i = 0; i < 4; ++i) {
            float xv = xs[ty * 4 + i][k];
            acc[i].x = fmaf(xv, wv.x, acc[i].x);
            acc[i].y = fmaf(xv, wv.y, acc[i].y);
            acc[i].z = fmaf(xv, wv.z, acc[i].z);
            acc[i].w = fmaf(xv, wv.w, acc[i].w);
        }
    }
#pragma unroll
    for (int i = 0; i < 4; ++i) {
        int row = row0 + ty * 4 + i;
        if (row < n) ((float4*)(h + (size_t)row * D))[tx] = acc[i];
    }
}

__global__ __launch_bounds__(128) void spmm_row(const float* __restrict__ h,
                                                const int* __restrict__ rows,
                                                const int* __restrict__ cols,
                                                const float* __restrict__ vals,
                                                float* __restrict__ out, int n_edges) {
    const int r = blockIdx.x, d = threadIdx.x;
    int lo = 0, hi = n_edges;
    while (lo < hi) { int m = (lo + hi) >> 1; if (rows[m] < r) lo = m + 1; else hi = m; }
    const int start = lo;
    hi = n_edges;
    while (lo < hi) { int m = (lo + hi) >> 1; if (rows[m] <= r) lo = m + 1; else hi = m; }
    const int end = lo;
    float acc = 0.f;
    for (int e = start; e < end; ++e)
        acc = fmaf(vals[e], h[(size_t)cols[e] * D + d], acc);
    out[(size_t)r * D + d] = fmaxf(acc, 0.f);
}

__global__ __launch_bounds__(128) void fused_fallback(
        const float* __restrict__ x, const float* __restrict__ w,
        const int* __restrict__ rows, const int* __restrict__ cols,
        const float* __restrict__ vals, float* __restrict__ out, int n_edges) {
    const int r = blockIdx.x, d = threadIdx.x;
    int lo = 0, hi = n_edges;
    while (lo < hi) { int m = (lo + hi) >> 1; if (rows[m] < r) lo = m + 1; else hi = m; }
    const int start = lo;
    hi = n_edges;
    while (lo < hi) { int m = (lo + hi) >> 1; if (rows[m] <= r) lo = m + 1; else hi = m; }
    const int end = lo;
    float acc = 0.f;
    for (int e = start; e < end; ++e) {
        int c = cols[e]; float v = vals[e];
        float hcd = 0.f;
        for (int k = 0; k < D; ++k)
            hcd = fmaf(x[(size_t)c * D + k], w[(size_t)k * D + d], hcd);
        acc = fmaf(v, hcd, acc);
    }
    out[(size_t)r * D + d] = fmaxf(acc, 0.f);
}

// ===========================================================================
extern "C" void kernel_launch(void* const* d_in, const int* in_sizes, int n_in,
                              void* d_out, int out_size, void* d_ws, size_t ws_size,
                              hipStream_t stream) {
    const float* x    = (const float*)d_in[0];
    const float* w    = (const float*)d_in[1];
    const int*   rows = (const int*)d_in[2];
    const int*   cols = (const int*)d_in[3];
    const float* vals = (const float*)d_in[4];
    float* out = (float*)d_out;

    const int n_nodes = in_sizes[0] / D;              // 50000
    const int n_edges = in_sizes[2];                  // 800000
    const int n_pad   = (n_nodes + 63) & ~63;         // 50048

    const size_t h_bytes  = (size_t)n_pad * D * sizeof(unsigned short);  // 12.8 MB
    const size_t rp_off   = h_bytes;
    const size_t need     = rp_off + (size_t)(n_nodes + 1) * sizeof(int);
    const size_t hf_bytes = (size_t)n_nodes * D * sizeof(float);

    if (ws_size >= need) {
        unsigned short* h  = (unsigned short*)d_ws;
        int*            rp = (int*)((char*)d_ws + rp_off);

        const int gemm_blocks = n_pad / 64;                      // 782
        const int rp_blocks   = (n_edges + 255) / 256;           // 3125
        fused_gemm_rp<<<gemm_blocks + rp_blocks, 256, 0, stream>>>(
            x, w, rows, h, rp, n_nodes, n_edges, gemm_blocks);

        spmm_bf16_b2<<<(n_nodes + 3) / 4, 256, 0, stream>>>(h, rp, cols, vals, out, n_nodes);
    } else if (ws_size >= hf_bytes) {
        float* hf = (float*)d_ws;
        gemm128<<<(n_nodes + GEMM_ROWS - 1) / GEMM_ROWS, 256, 0, stream>>>(x, w, hf, n_nodes);
        spmm_row<<<n_nodes, 128, 0, stream>>>(hf, rows, cols, vals, out, n_edges);
    } else {
        fused_fallback<<<n_nodes, 128, 0, stream>>>(x, w, rows, cols, vals, out, n_edges);
    }
}